// Round 1
// baseline (179.592 us; speedup 1.0000x reference)
//
#include <hip/hip_runtime.h>

// CondMul: out[n] = input[n] @ w[inds[n]] + b[inds[n]]
// N=262144 rows, 1024 experts, in=out=32, fp32.
//
// v2: counting-sort by expert, then one block per expert with w cached in
// REGISTERS (not LDS — v1 re-read the same 4KiB from LDS every 32-row
// iteration: ~1M ds_read_b128 = ~20us of LDS-pipe issue). Scatter order
// within a class bucket is irrelevant to the output, so the deterministic
// per-block cursor machinery (serial 64-iter RMW loop in the scan kernel)
// is replaced by global atomic cursors.

#define N_ROWS      262144
#define N_CLASSES   1024
#define IN_F        32
#define OUT_F       32
#define HB          128
#define ROWS_PER_HB (N_ROWS / HB)   // 2048, exact

// ---------------- K1: per-block histogram (LDS atomics) ----------------
__global__ __launch_bounds__(256) void k_hist(const int* __restrict__ inds,
                                              int* __restrict__ bc) {
    __shared__ int h[N_CLASSES];
    const int tid = threadIdx.x;
    for (int c = tid; c < N_CLASSES; c += 256) h[c] = 0;
    __syncthreads();
    const int base = blockIdx.x * ROWS_PER_HB;
    for (int k = 0; k < ROWS_PER_HB; k += 256)
        atomicAdd(&h[inds[base + k + tid]], 1);
    __syncthreads();
    for (int c = tid; c < N_CLASSES; c += 256)
        bc[blockIdx.x * N_CLASSES + c] = h[c];
}

// ------- K2: single block; reduce per-class totals, scan, init cursors -------
__global__ __launch_bounds__(1024) void k_scan(const int* __restrict__ bc,
                                               int* __restrict__ cls_off,
                                               int* __restrict__ cursor) {
    __shared__ int s[N_CLASSES];
    const int c = threadIdx.x;  // 1024 threads == N_CLASSES
    int total = 0;
#pragma unroll 8
    for (int b = 0; b < HB; ++b) total += bc[b * N_CLASSES + c];
    s[c] = total;
    __syncthreads();
    // Hillis-Steele inclusive scan over classes
    for (int off = 1; off < N_CLASSES; off <<= 1) {
        int v = (c >= off) ? s[c - off] : 0;
        __syncthreads();
        s[c] += v;
        __syncthreads();
    }
    const int base = s[c] - total;  // exclusive prefix
    cls_off[c] = base;
    cursor[c]  = base;
    if (c == N_CLASSES - 1) cls_off[N_CLASSES] = s[c];  // == N_ROWS
}

// ---------------- K3: scatter row ids into buckets (global cursors) ----------------
// Order within a bucket is nondeterministic; out[row] does not depend on it.
__global__ __launch_bounds__(256) void k_scatter(const int* __restrict__ inds,
                                                 int* __restrict__ cursor,
                                                 int* __restrict__ rowids) {
    const int base = blockIdx.x * ROWS_PER_HB;
    const int tid = threadIdx.x;
    for (int k = 0; k < ROWS_PER_HB; k += 256) {
        const int row = base + k + tid;
        const int c = inds[row];
        const int pos = atomicAdd(&cursor[c], 1);
        rowids[pos] = row;
    }
}

// ---------------- K4: one block per expert, w in REGISTERS ----------------
// 256 threads = 4 waves. Lane -> (row slot rg = tid>>3, out-quad oq = tid&7).
// Each lane holds its w column slice w[0..31][oq*4..oq*4+3] in 32 float4 regs,
// loaded ONCE per block. Per iteration the block does 64 rows in 2 streams
// (A: rows it*64+rg, B: +32) for load-level parallelism: 16 float4 global
// loads in flight, then 256 FMAs across two independent acc chains.
__global__ __launch_bounds__(256, 2) void k_condmul(const float* __restrict__ input,
                                                    const float* __restrict__ w,
                                                    const float* __restrict__ bias,
                                                    const int* __restrict__ rowids,
                                                    const int* __restrict__ cls_off,
                                                    float* __restrict__ out) {
    const int cls = blockIdx.x;
    const int tid = threadIdx.x;
    const int oq = tid & 7;   // float4 column index (outputs oq*4 .. oq*4+3)
    const int rg = tid >> 3;  // 0..31 row slot

    const int start = cls_off[cls];
    const int count = cls_off[cls + 1] - start;
    if (count <= 0) return;

    // w column slice into registers: 32 x float4 = 128 VGPRs.
    // Wave pattern per load: lanes 0..7 read 128B contiguous, rg-groups
    // broadcast the same addresses -> 128B/instr fetched.
    const float4* w4 = (const float4*)(w + (size_t)cls * (IN_F * OUT_F));
    float4 wr[IN_F];
#pragma unroll
    for (int j = 0; j < IN_F; ++j) wr[j] = w4[j * (OUT_F / 4) + oq];

    const float4 bv = ((const float4*)(bias + (size_t)cls * OUT_F))[oq];

    const int iters = (count + 63) >> 6;
    for (int it = 0; it < iters; ++it) {
        const int riA = it * 64 + rg;
        const int riB = riA + 32;
        const bool va = riA < count;
        const bool vb = riB < count;
        const int rowA = rowids[start + (va ? riA : count - 1)];
        const int rowB = rowids[start + (vb ? riB : count - 1)];

        const float4* xa4 = (const float4*)(input + (size_t)rowA * IN_F);
        const float4* xb4 = (const float4*)(input + (size_t)rowB * IN_F);
        float4 xa[8], xb[8];
#pragma unroll
        for (int j = 0; j < 8; ++j) xa[j] = xa4[j];
#pragma unroll
        for (int j = 0; j < 8; ++j) xb[j] = xb4[j];

        float4 accA = bv;
        float4 accB = bv;
#pragma unroll
        for (int j = 0; j < 8; ++j) {
            const float a0 = xa[j].x, a1 = xa[j].y, a2 = xa[j].z, a3 = xa[j].w;
            const float b0 = xb[j].x, b1 = xb[j].y, b2 = xb[j].z, b3 = xb[j].w;
            const float4 w0 = wr[j * 4 + 0];
            const float4 w1 = wr[j * 4 + 1];
            const float4 w2 = wr[j * 4 + 2];
            const float4 w3 = wr[j * 4 + 3];
            accA.x += a0 * w0.x; accA.y += a0 * w0.y; accA.z += a0 * w0.z; accA.w += a0 * w0.w;
            accA.x += a1 * w1.x; accA.y += a1 * w1.y; accA.z += a1 * w1.z; accA.w += a1 * w1.w;
            accA.x += a2 * w2.x; accA.y += a2 * w2.y; accA.z += a2 * w2.z; accA.w += a2 * w2.w;
            accA.x += a3 * w3.x; accA.y += a3 * w3.y; accA.z += a3 * w3.z; accA.w += a3 * w3.w;
            accB.x += b0 * w0.x; accB.y += b0 * w0.y; accB.z += b0 * w0.z; accB.w += b0 * w0.w;
            accB.x += b1 * w1.x; accB.y += b1 * w1.y; accB.z += b1 * w1.z; accB.w += b1 * w1.w;
            accB.x += b2 * w2.x; accB.y += b2 * w2.y; accB.z += b2 * w2.z; accB.w += b2 * w2.w;
            accB.x += b3 * w3.x; accB.y += b3 * w3.y; accB.z += b3 * w3.z; accB.w += b3 * w3.w;
        }
        if (va) ((float4*)(out + (size_t)rowA * OUT_F))[oq] = accA;
        if (vb) ((float4*)(out + (size_t)rowB * OUT_F))[oq] = accB;
    }
}

// ---------------- fallback: direct gather (used only if ws too small) ----------------
__global__ __launch_bounds__(256) void k_naive(const float* __restrict__ input,
                                               const int* __restrict__ inds,
                                               const float* __restrict__ w,
                                               const float* __restrict__ bias,
                                               float* __restrict__ out) {
    const int tid = threadIdx.x;
    const int oq = tid & 7;
    const int rg = tid >> 3;
    const int row = blockIdx.x * 32 + rg;
    if (row >= N_ROWS) return;
    const int c = inds[row];
    const float4* xin = (const float4*)(input + (size_t)row * IN_F);
    const float4* wr = (const float4*)(w + (size_t)c * IN_F * OUT_F);
    float4 acc = ((const float4*)(bias + (size_t)c * OUT_F))[oq];
#pragma unroll
    for (int j = 0; j < 8; ++j) {
        const float4 xv = xin[j];
        const float a0 = xv.x, a1 = xv.y, a2 = xv.z, a3 = xv.w;
        const float4 w0 = wr[(j * 4 + 0) * (OUT_F / 4) + oq];
        const float4 w1 = wr[(j * 4 + 1) * (OUT_F / 4) + oq];
        const float4 w2 = wr[(j * 4 + 2) * (OUT_F / 4) + oq];
        const float4 w3 = wr[(j * 4 + 3) * (OUT_F / 4) + oq];
        acc.x += a0 * w0.x; acc.y += a0 * w0.y; acc.z += a0 * w0.z; acc.w += a0 * w0.w;
        acc.x += a1 * w1.x; acc.y += a1 * w1.y; acc.z += a1 * w1.z; acc.w += a1 * w1.w;
        acc.x += a2 * w2.x; acc.y += a2 * w2.y; acc.z += a2 * w2.z; acc.w += a2 * w2.w;
        acc.x += a3 * w3.x; acc.y += a3 * w3.y; acc.z += a3 * w3.z; acc.w += a3 * w3.w;
    }
    ((float4*)(out + (size_t)row * OUT_F))[oq] = acc;
}

extern "C" void kernel_launch(void* const* d_in, const int* in_sizes, int n_in,
                              void* d_out, int out_size, void* d_ws, size_t ws_size,
                              hipStream_t stream) {
    const float* input = (const float*)d_in[0];  // [N, 32] fp32
    const int*   inds  = (const int*)d_in[1];    // [N] int32
    const float* w     = (const float*)d_in[2];  // [1024, 32, 32] fp32
    const float* bias  = (const float*)d_in[3];  // [1024, 1, 32] fp32
    float* out = (float*)d_out;                  // [N, 32] fp32

    // ws layout (ints): bc[HB][1024] | cls_off[1025] (+3 pad) | cursor[1024] | rowids[N]
    int* ws = (int*)d_ws;
    int* bc      = ws;
    int* cls_off = ws + HB * N_CLASSES;
    int* cursor  = cls_off + N_CLASSES + 1 + 3;
    int* rowids  = cursor + N_CLASSES;
    const size_t need = (size_t)(HB * N_CLASSES + N_CLASSES + 4 + N_CLASSES + N_ROWS) * sizeof(int);

    if (ws_size >= need) {
        k_hist<<<HB, 256, 0, stream>>>(inds, bc);
        k_scan<<<1, 1024, 0, stream>>>(bc, cls_off, cursor);
        k_scatter<<<HB, 256, 0, stream>>>(inds, cursor, rowids);
        k_condmul<<<N_CLASSES, 256, 0, stream>>>(input, w, bias, rowids, cls_off, out);
    } else {
        k_naive<<<N_ROWS / 32, 256, 0, stream>>>(input, inds, w, bias, out);
    }
}

// Round 2
// 155.416 us; speedup vs baseline: 1.1556x; 1.1556x over previous
//
#include <hip/hip_runtime.h>

// CondMul: out[n] = input[n] @ w[inds[n]] + b[inds[n]]
// N=262144 rows, 1024 experts, in=out=32, fp32.
//
// v3: counting-sort by expert with DETERMINISTIC per-block offsets (LDS
// cursors — v2's global atomic cursors cost 55us: 256-deep serialized RMW
// chains per cursor + cross-XCD cacheline ping-pong). Scan kernel caches
// per-block counts in registers so the offset rewrite needs no global
// re-read. Condmul keeps v2's register-cached w (v1 re-read the same 4KiB
// from LDS every iteration: ~1M ds_read_b128 = ~20us of LDS-pipe issue).

#define N_ROWS      262144
#define N_CLASSES   1024
#define IN_F        32
#define OUT_F       32
#define HB          64
#define ROWS_PER_HB (N_ROWS / HB)   // 4096, exact

// ---------------- K1: per-block histogram (LDS atomics) ----------------
__global__ __launch_bounds__(256) void k_hist(const int* __restrict__ inds,
                                              int* __restrict__ bc) {
    __shared__ int h[N_CLASSES];
    const int tid = threadIdx.x;
    for (int c = tid; c < N_CLASSES; c += 256) h[c] = 0;
    __syncthreads();
    const int base = blockIdx.x * ROWS_PER_HB;
    for (int k = 0; k < ROWS_PER_HB; k += 256)
        atomicAdd(&h[inds[base + k + tid]], 1);
    __syncthreads();
    for (int c = tid; c < N_CLASSES; c += 256)
        bc[blockIdx.x * N_CLASSES + c] = h[c];
}

// ------- K2: single block; totals (counts cached in regs), scan, offsets -------
// Thread c handles class c. Loads bc[b][c] for all b (coalesced across the
// 1024 threads at each b), keeps them in registers (HB=64 VGPRs, static
// indexing via full unroll), scans class totals in LDS, then writes the
// per-(block,class) start offsets back without re-reading bc.
__global__ __launch_bounds__(1024) void k_scan(int* __restrict__ bc,
                                               int* __restrict__ cls_off) {
    __shared__ int s[N_CLASSES];
    const int c = threadIdx.x;  // 1024 threads == N_CLASSES
    int v[HB];
    int total = 0;
#pragma unroll
    for (int b = 0; b < HB; ++b) {
        v[b] = bc[b * N_CLASSES + c];
        total += v[b];
    }
    s[c] = total;
    __syncthreads();
    // Hillis-Steele inclusive scan over classes
    for (int off = 1; off < N_CLASSES; off <<= 1) {
        int t = (c >= off) ? s[c - off] : 0;
        __syncthreads();
        s[c] += t;
        __syncthreads();
    }
    int run = s[c] - total;  // exclusive prefix = class base
    cls_off[c] = run;
    if (c == N_CLASSES - 1) cls_off[N_CLASSES] = s[c];  // == N_ROWS
#pragma unroll
    for (int b = 0; b < HB; ++b) {
        const int t = v[b];
        bc[b * N_CLASSES + c] = run;  // start offset for (hist-block b, class c)
        run += t;
    }
}

// ---------------- K3: scatter row ids into buckets (LDS cursors) ----------------
// Deterministic: block b's cursor for class c starts at the precomputed
// global offset; all atomics are LDS-local (no cross-XCD traffic).
__global__ __launch_bounds__(256) void k_scatter(const int* __restrict__ inds,
                                                 const int* __restrict__ bc,
                                                 int* __restrict__ rowids) {
    __shared__ int cur[N_CLASSES];
    const int tid = threadIdx.x;
    for (int c = tid; c < N_CLASSES; c += 256)
        cur[c] = bc[blockIdx.x * N_CLASSES + c];
    __syncthreads();
    const int base = blockIdx.x * ROWS_PER_HB;
    for (int k = 0; k < ROWS_PER_HB; k += 256) {
        const int row = base + k + tid;
        const int c = inds[row];
        const int pos = atomicAdd(&cur[c], 1);
        rowids[pos] = row;
    }
}

// ---------------- K4: one block per expert, w in REGISTERS ----------------
// 256 threads = 4 waves. Lane -> (row slot rg = tid>>3, out-quad oq = tid&7).
// Each lane holds its w column slice w[0..31][oq*4..oq*4+3] in 32 float4 regs,
// loaded ONCE per block. Per iteration the block does 64 rows in 2 streams
// (A: rows it*64+rg, B: +32) for load-level parallelism: 16 float4 global
// loads in flight, then 256 FMAs across two independent acc chains.
__global__ __launch_bounds__(256, 2) void k_condmul(const float* __restrict__ input,
                                                    const float* __restrict__ w,
                                                    const float* __restrict__ bias,
                                                    const int* __restrict__ rowids,
                                                    const int* __restrict__ cls_off,
                                                    float* __restrict__ out) {
    const int cls = blockIdx.x;
    const int tid = threadIdx.x;
    const int oq = tid & 7;   // float4 column index (outputs oq*4 .. oq*4+3)
    const int rg = tid >> 3;  // 0..31 row slot

    const int start = cls_off[cls];
    const int count = cls_off[cls + 1] - start;
    if (count <= 0) return;

    // w column slice into registers: 32 x float4 = 128 VGPRs.
    const float4* w4 = (const float4*)(w + (size_t)cls * (IN_F * OUT_F));
    float4 wr[IN_F];
#pragma unroll
    for (int j = 0; j < IN_F; ++j) wr[j] = w4[j * (OUT_F / 4) + oq];

    const float4 bv = ((const float4*)(bias + (size_t)cls * OUT_F))[oq];

    const int iters = (count + 63) >> 6;
    for (int it = 0; it < iters; ++it) {
        const int riA = it * 64 + rg;
        const int riB = riA + 32;
        const bool va = riA < count;
        const bool vb = riB < count;
        const int rowA = rowids[start + (va ? riA : count - 1)];
        const int rowB = rowids[start + (vb ? riB : count - 1)];

        const float4* xa4 = (const float4*)(input + (size_t)rowA * IN_F);
        const float4* xb4 = (const float4*)(input + (size_t)rowB * IN_F);
        float4 xa[8], xb[8];
#pragma unroll
        for (int j = 0; j < 8; ++j) xa[j] = xa4[j];
#pragma unroll
        for (int j = 0; j < 8; ++j) xb[j] = xb4[j];

        float4 accA = bv;
        float4 accB = bv;
#pragma unroll
        for (int j = 0; j < 8; ++j) {
            const float a0 = xa[j].x, a1 = xa[j].y, a2 = xa[j].z, a3 = xa[j].w;
            const float b0 = xb[j].x, b1 = xb[j].y, b2 = xb[j].z, b3 = xb[j].w;
            const float4 w0 = wr[j * 4 + 0];
            const float4 w1 = wr[j * 4 + 1];
            const float4 w2 = wr[j * 4 + 2];
            const float4 w3 = wr[j * 4 + 3];
            accA.x += a0 * w0.x; accA.y += a0 * w0.y; accA.z += a0 * w0.z; accA.w += a0 * w0.w;
            accA.x += a1 * w1.x; accA.y += a1 * w1.y; accA.z += a1 * w1.z; accA.w += a1 * w1.w;
            accA.x += a2 * w2.x; accA.y += a2 * w2.y; accA.z += a2 * w2.z; accA.w += a2 * w2.w;
            accA.x += a3 * w3.x; accA.y += a3 * w3.y; accA.z += a3 * w3.z; accA.w += a3 * w3.w;
            accB.x += b0 * w0.x; accB.y += b0 * w0.y; accB.z += b0 * w0.z; accB.w += b0 * w0.w;
            accB.x += b1 * w1.x; accB.y += b1 * w1.y; accB.z += b1 * w1.z; accB.w += b1 * w1.w;
            accB.x += b2 * w2.x; accB.y += b2 * w2.y; accB.z += b2 * w2.z; accB.w += b2 * w2.w;
            accB.x += b3 * w3.x; accB.y += b3 * w3.y; accB.z += b3 * w3.z; accB.w += b3 * w3.w;
        }
        if (va) ((float4*)(out + (size_t)rowA * OUT_F))[oq] = accA;
        if (vb) ((float4*)(out + (size_t)rowB * OUT_F))[oq] = accB;
    }
}

// ---------------- fallback: direct gather (used only if ws too small) ----------------
__global__ __launch_bounds__(256) void k_naive(const float* __restrict__ input,
                                               const int* __restrict__ inds,
                                               const float* __restrict__ w,
                                               const float* __restrict__ bias,
                                               float* __restrict__ out) {
    const int tid = threadIdx.x;
    const int oq = tid & 7;
    const int rg = tid >> 3;
    const int row = blockIdx.x * 32 + rg;
    if (row >= N_ROWS) return;
    const int c = inds[row];
    const float4* xin = (const float4*)(input + (size_t)row * IN_F);
    const float4* wr = (const float4*)(w + (size_t)c * IN_F * OUT_F);
    float4 acc = ((const float4*)(bias + (size_t)c * OUT_F))[oq];
#pragma unroll
    for (int j = 0; j < 8; ++j) {
        const float4 xv = xin[j];
        const float a0 = xv.x, a1 = xv.y, a2 = xv.z, a3 = xv.w;
        const float4 w0 = wr[(j * 4 + 0) * (OUT_F / 4) + oq];
        const float4 w1 = wr[(j * 4 + 1) * (OUT_F / 4) + oq];
        const float4 w2 = wr[(j * 4 + 2) * (OUT_F / 4) + oq];
        const float4 w3 = wr[(j * 4 + 3) * (OUT_F / 4) + oq];
        acc.x += a0 * w0.x; acc.y += a0 * w0.y; acc.z += a0 * w0.z; acc.w += a0 * w0.w;
        acc.x += a1 * w1.x; acc.y += a1 * w1.y; acc.z += a1 * w1.z; acc.w += a1 * w1.w;
        acc.x += a2 * w2.x; acc.y += a2 * w2.y; acc.z += a2 * w2.z; acc.w += a2 * w2.w;
        acc.x += a3 * w3.x; acc.y += a3 * w3.y; acc.z += a3 * w3.z; acc.w += a3 * w3.w;
    }
    ((float4*)(out + (size_t)row * OUT_F))[oq] = acc;
}

extern "C" void kernel_launch(void* const* d_in, const int* in_sizes, int n_in,
                              void* d_out, int out_size, void* d_ws, size_t ws_size,
                              hipStream_t stream) {
    const float* input = (const float*)d_in[0];  // [N, 32] fp32
    const int*   inds  = (const int*)d_in[1];    // [N] int32
    const float* w     = (const float*)d_in[2];  // [1024, 32, 32] fp32
    const float* bias  = (const float*)d_in[3];  // [1024, 1, 32] fp32
    float* out = (float*)d_out;                  // [N, 32] fp32

    // ws layout (ints): bc[HB][1024] | cls_off[1025] (+3 pad) | rowids[N]
    int* ws = (int*)d_ws;
    int* bc      = ws;
    int* cls_off = ws + HB * N_CLASSES;
    int* rowids  = cls_off + N_CLASSES + 1 + 3;
    const size_t need = (size_t)(HB * N_CLASSES + N_CLASSES + 4 + N_ROWS) * sizeof(int);

    if (ws_size >= need) {
        k_hist<<<HB, 256, 0, stream>>>(inds, bc);
        k_scan<<<1, 1024, 0, stream>>>(bc, cls_off);
        k_scatter<<<HB, 256, 0, stream>>>(inds, bc, rowids);
        k_condmul<<<N_CLASSES, 256, 0, stream>>>(input, w, bias, rowids, cls_off, out);
    } else {
        k_naive<<<N_ROWS / 32, 256, 0, stream>>>(input, inds, w, bias, out);
    }
}

// Round 4
// 147.672 us; speedup vs baseline: 1.2162x; 1.0524x over previous
//
#include <hip/hip_runtime.h>

// CondMul: out[n] = input[n] @ w[inds[n]] + b[inds[n]]
// N=262144 rows, 1024 experts, in=out=32, fp32.
//
// v4 (resubmit; R3 run died on container infra, no data): counting-sort by
// expert, and the scatter pass PHYSICALLY PERMUTES the input rows into xs[]
// (streaming coalesced read, scattered 128B write — writes don't stall).
// The condmul then STREAMS xs contiguously per class; the only random access
// left is the output write. This removes the dependent random-gather that
// made condmul latency-bound (v1/v3), without the VGPR blowup of
// register-cached w (v3: 2 waves/SIMD, +34us regression). w stays in LDS
// (broadcast reads, ~110 VGPR); 2 row-streams per iteration halve per-row
// LDS issue.

#define N_ROWS      262144
#define N_CLASSES   1024
#define IN_F        32
#define OUT_F       32
#define HB          64
#define ROWS_PER_HB (N_ROWS / HB)   // 4096, exact

// ---------------- K1: per-block histogram (LDS atomics) ----------------
__global__ __launch_bounds__(1024) void k_hist(const int* __restrict__ inds,
                                               int* __restrict__ bc) {
    __shared__ int h[N_CLASSES];
    const int tid = threadIdx.x;
    h[tid] = 0;
    __syncthreads();
    const int base = blockIdx.x * ROWS_PER_HB;
    for (int k = 0; k < ROWS_PER_HB; k += 1024)
        atomicAdd(&h[inds[base + k + tid]], 1);
    __syncthreads();
    bc[blockIdx.x * N_CLASSES + tid] = h[tid];
}

// ------- K2: single block; per-class totals, scan, per-block starts -------
__global__ __launch_bounds__(1024) void k_scan(int* __restrict__ bc,
                                               int* __restrict__ cls_off) {
    __shared__ int s[N_CLASSES];
    const int c = threadIdx.x;  // 1024 threads == N_CLASSES
    int total = 0;
    for (int b = 0; b < HB; ++b) total += bc[b * N_CLASSES + c];
    s[c] = total;
    __syncthreads();
    // Hillis-Steele inclusive scan over classes
    for (int off = 1; off < N_CLASSES; off <<= 1) {
        int v = (c >= off) ? s[c - off] : 0;
        __syncthreads();
        s[c] += v;
        __syncthreads();
    }
    int run = s[c] - total;  // exclusive prefix = class base
    cls_off[c] = run;
    if (c == N_CLASSES - 1) cls_off[N_CLASSES] = s[c];  // == N_ROWS
    for (int b = 0; b < HB; ++b) {
        const int t = bc[b * N_CLASSES + c];
        bc[b * N_CLASSES + c] = run;  // start offset for (hist-block b, class c)
        run += t;
    }
}

// ------- K3: scatter rows into sorted order (LDS cursors + row copy) -------
// Phase 1: each thread claims a slot for its row (LDS atomic, deterministic
// per-block range). Phase 2: cooperative copy, 8 lanes per row -> the input
// read is fully coalesced (1KB/wave); the 128B row write to xs[pos] is
// scattered but fire-and-forget.
__global__ __launch_bounds__(1024) void k_scatter(const int* __restrict__ inds,
                                                  const int* __restrict__ bc,
                                                  int* __restrict__ rowids,
                                                  float4* __restrict__ xs4,
                                                  const float4* __restrict__ in4) {
    __shared__ int cur[N_CLASSES];
    __shared__ int poss[1024];
    const int tid = threadIdx.x;
    cur[tid] = bc[blockIdx.x * N_CLASSES + tid];
    const int base = blockIdx.x * ROWS_PER_HB;
    const int q = tid & 7;        // float4 index within a row
    const int rs = tid >> 3;      // 0..127 row slot within a copy subiter
    for (int o = 0; o < ROWS_PER_HB; o += 1024) {
        __syncthreads();          // cur ready / poss free for reuse
        const int row = base + o + tid;
        const int c = inds[row];
        const int pos = atomicAdd(&cur[c], 1);
        poss[tid] = pos;
        rowids[pos] = row;
        __syncthreads();
        // copy 1024 rows: 8 subiters x 128 rows, 8 lanes per row
#pragma unroll
        for (int s = 0; s < 8; ++s) {
            const int r = s * 128 + rs;
            const int p = poss[r];
            xs4[(size_t)p * 8 + q] = in4[(size_t)(base + o + r) * 8 + q];
        }
    }
}

// ---------------- K4: one block per expert, STREAMING input ----------------
// 256 threads = 4 waves. Lane -> (row slot rg = tid>>3, out-quad oq = tid&7).
// w staged in LDS once (4KB, broadcast reads). Input rows come from xs in
// sorted order -> contiguous coalesced loads. 2 row-streams per iteration
// (64 rows) share each LDS w read. Only the out write is scattered.
__global__ __launch_bounds__(256) void k_condmul(const float4* __restrict__ xs4,
                                                 const float* __restrict__ w,
                                                 const float* __restrict__ bias,
                                                 const int* __restrict__ rowids,
                                                 const int* __restrict__ cls_off,
                                                 float* __restrict__ out) {
    __shared__ float wlds[IN_F * OUT_F];  // 4 KiB
    const int cls = blockIdx.x;
    const int tid = threadIdx.x;
    ((float4*)wlds)[tid] = ((const float4*)(w + (size_t)cls * IN_F * OUT_F))[tid];

    const int oq = tid & 7;   // output quad
    const int rg = tid >> 3;  // row slot 0..31
    const int start = cls_off[cls];
    const int count = cls_off[cls + 1] - start;
    const float4 bv = ((const float4*)(bias + (size_t)cls * OUT_F))[oq];
    __syncthreads();
    if (count <= 0) return;

    const float4* wl4 = (const float4*)wlds;
    const int iters = (count + 63) >> 6;
    for (int it = 0; it < iters; ++it) {
        const int riA = it * 64 + rg;
        const int riB = riA + 32;
        const bool va = riA < count;
        const bool vb = riB < count;
        const int idxA = start + (va ? riA : count - 1);
        const int idxB = start + (vb ? riB : count - 1);

        float4 xa[8], xb[8];
#pragma unroll
        for (int j = 0; j < 8; ++j) xa[j] = xs4[(size_t)idxA * 8 + j];
#pragma unroll
        for (int j = 0; j < 8; ++j) xb[j] = xs4[(size_t)idxB * 8 + j];
        const int rowA = rowids[idxA];
        const int rowB = rowids[idxB];

        float4 accA = bv;
        float4 accB = bv;
#pragma unroll
        for (int j = 0; j < 8; ++j) {
            const float a0 = xa[j].x, a1 = xa[j].y, a2 = xa[j].z, a3 = xa[j].w;
            const float b0 = xb[j].x, b1 = xb[j].y, b2 = xb[j].z, b3 = xb[j].w;
            const float4 w0 = wl4[(j * 4 + 0) * (OUT_F / 4) + oq];
            const float4 w1 = wl4[(j * 4 + 1) * (OUT_F / 4) + oq];
            const float4 w2 = wl4[(j * 4 + 2) * (OUT_F / 4) + oq];
            const float4 w3 = wl4[(j * 4 + 3) * (OUT_F / 4) + oq];
            accA.x += a0 * w0.x; accA.y += a0 * w0.y; accA.z += a0 * w0.z; accA.w += a0 * w0.w;
            accA.x += a1 * w1.x; accA.y += a1 * w1.y; accA.z += a1 * w1.z; accA.w += a1 * w1.w;
            accA.x += a2 * w2.x; accA.y += a2 * w2.y; accA.z += a2 * w2.z; accA.w += a2 * w2.w;
            accA.x += a3 * w3.x; accA.y += a3 * w3.y; accA.z += a3 * w3.z; accA.w += a3 * w3.w;
            accB.x += b0 * w0.x; accB.y += b0 * w0.y; accB.z += b0 * w0.z; accB.w += b0 * w0.w;
            accB.x += b1 * w1.x; accB.y += b1 * w1.y; accB.z += b1 * w1.z; accB.w += b1 * w1.w;
            accB.x += b2 * w2.x; accB.y += b2 * w2.y; accB.z += b2 * w2.z; accB.w += b2 * w2.w;
            accB.x += b3 * w3.x; accB.y += b3 * w3.y; accB.z += b3 * w3.z; accB.w += b3 * w3.w;
        }
        if (va) ((float4*)(out + (size_t)rowA * OUT_F))[oq] = accA;
        if (vb) ((float4*)(out + (size_t)rowB * OUT_F))[oq] = accB;
    }
}

// ---------------- fallback: direct gather (used only if ws too small) ----------------
__global__ __launch_bounds__(256) void k_naive(const float* __restrict__ input,
                                               const int* __restrict__ inds,
                                               const float* __restrict__ w,
                                               const float* __restrict__ bias,
                                               float* __restrict__ out) {
    const int tid = threadIdx.x;
    const int oq = tid & 7;
    const int rg = tid >> 3;
    const int row = blockIdx.x * 32 + rg;
    if (row >= N_ROWS) return;
    const int c = inds[row];
    const float4* xin = (const float4*)(input + (size_t)row * IN_F);
    const float4* wr = (const float4*)(w + (size_t)c * IN_F * OUT_F);
    float4 acc = ((const float4*)(bias + (size_t)c * OUT_F))[oq];
#pragma unroll
    for (int j = 0; j < 8; ++j) {
        const float4 xv = xin[j];
        const float a0 = xv.x, a1 = xv.y, a2 = xv.z, a3 = xv.w;
        const float4 w0 = wr[(j * 4 + 0) * (OUT_F / 4) + oq];
        const float4 w1 = wr[(j * 4 + 1) * (OUT_F / 4) + oq];
        const float4 w2 = wr[(j * 4 + 2) * (OUT_F / 4) + oq];
        const float4 w3 = wr[(j * 4 + 3) * (OUT_F / 4) + oq];
        acc.x += a0 * w0.x; acc.y += a0 * w0.y; acc.z += a0 * w0.z; acc.w += a0 * w0.w;
        acc.x += a1 * w1.x; acc.y += a1 * w1.y; acc.z += a1 * w1.z; acc.w += a1 * w1.w;
        acc.x += a2 * w2.x; acc.y += a2 * w2.y; acc.z += a2 * w2.z; acc.w += a2 * w2.w;
        acc.x += a3 * w3.x; acc.y += a3 * w3.y; acc.z += a3 * w3.z; acc.w += a3 * w3.w;
    }
    ((float4*)(out + (size_t)row * OUT_F))[oq] = acc;
}

extern "C" void kernel_launch(void* const* d_in, const int* in_sizes, int n_in,
                              void* d_out, int out_size, void* d_ws, size_t ws_size,
                              hipStream_t stream) {
    const float* input = (const float*)d_in[0];  // [N, 32] fp32
    const int*   inds  = (const int*)d_in[1];    // [N] int32
    const float* w     = (const float*)d_in[2];  // [1024, 32, 32] fp32
    const float* bias  = (const float*)d_in[3];  // [1024, 1, 32] fp32
    float* out = (float*)d_out;                  // [N, 32] fp32

    // ws layout (ints): bc[HB][1024] | cls_off[1025+3 pad] | rowids[N] | xs[N*32 floats]
    int* ws = (int*)d_ws;
    int* bc      = ws;                                   // 65536 ints
    int* cls_off = ws + HB * N_CLASSES;                  // 1028 ints
    int* rowids  = cls_off + N_CLASSES + 1 + 3;          // N ints
    float* xs    = (float*)(rowids + N_ROWS);            // N*32 floats (16B aligned)
    const size_t need = (size_t)(HB * N_CLASSES + N_CLASSES + 4 + N_ROWS) * sizeof(int)
                      + (size_t)N_ROWS * IN_F * sizeof(float);

    if (ws_size >= need) {
        k_hist<<<HB, 1024, 0, stream>>>(inds, bc);
        k_scan<<<1, 1024, 0, stream>>>(bc, cls_off);
        k_scatter<<<HB, 1024, 0, stream>>>(inds, bc, rowids, (float4*)xs, (const float4*)input);
        k_condmul<<<N_CLASSES, 256, 0, stream>>>((const float4*)xs, w, bias, rowids, cls_off, out);
    } else {
        k_naive<<<N_ROWS / 32, 256, 0, stream>>>(input, inds, w, bias, out);
    }
}